// Round 2
// baseline (911.257 us; speedup 1.0000x reference)
//
#include <hip/hip_runtime.h>
#include <cstdint>
#include <cstddef>

#define E_    100
#define N_    50
#define B_    8192
#define L_    1000
#define NPAIR 4950

// ---------------- K0a: tiny precomputes (attention u/c vectors, bias copies, pair table, vv) ----
__global__ __launch_bounds__(256) void k0a(const float* __restrict__ v,
        const float* __restrict__ W1, const float* __restrict__ b1, const float* __restrict__ W2,
        const float* __restrict__ W3, const float* __restrict__ b3, const float* __restrict__ W4,
        const float* __restrict__ b5, const float* __restrict__ b6, const float* __restrict__ b7,
        float* __restrict__ usf, float* __restrict__ csf,
        float* __restrict__ b5f, float* __restrict__ b6f, float* __restrict__ b7f,
        float* __restrict__ vvp, int* __restrict__ pairIJ) {
    int tid = threadIdx.x;
    if (tid < 200) {
        int h = (tid >= 100); int e = tid - 100 * h;
        const float* Wa = h ? W3 : W1; const float* Wb = h ? W4 : W2;
        float u = 0.f;
        for (int t = 0; t < 8; t++) u += Wa[t * 100 + e] * Wb[t];
        usf[tid] = u;
    } else if (tid < 202) {
        int h = tid - 200;
        const float* bb = h ? b3 : b1; const float* Wb = h ? W4 : W2;
        float c = 0.f;
        for (int t = 0; t < 8; t++) c += bb[t] * Wb[t];
        csf[h] = c;
    }
    if (tid < 100) {
        b5f[tid] = b5[tid];
        b6f[tid] = b6[tid];
        b7f[tid] = b7[tid];
        int i = tid;
        int base = i * 99 - (i * (i - 1)) / 2;  // start of triu row i (k=1), i-major
        float vi0 = v[i * 4 + 0], vi1 = v[i * 4 + 1];
        float vi2 = v[i * 4 + 2], vi3 = v[i * 4 + 3];
        for (int j = i + 1; j < 100; j++) {
            int p = base + (j - i - 1);
            pairIJ[p] = (i << 8) | j;
            vvp[p] = vi0 * v[j * 4 + 0] + vi1 * v[j * 4 + 1]
                   + vi2 * v[j * 4 + 2] + vi3 * v[j * 4 + 3];
        }
    }
}

// ---------------- K0b: transpose W5,W6,W8 ----------------
__global__ __launch_bounds__(256) void k0b(const float* __restrict__ W5, const float* __restrict__ W6,
        const float* __restrict__ W8, float* __restrict__ W5fT, float* __restrict__ W6fT,
        float* __restrict__ W8fT) {
    int gid = blockIdx.x * 256 + threadIdx.x;
    if (gid < 20000) {                       // W5fT[j][t] = W5[t][j], j<200,t<100
        int o = gid; int j = o / 100; int t = o - 100 * j;
        W5fT[o] = W5[t * 200 + j];
    } else if (gid < 30000) {                // W6fT[j][t] = W6[t][j]
        int o = gid - 20000; int j = o / 100; int t = o - 100 * j;
        W6fT[o] = W6[t * 100 + j];
    } else if (gid < 50000) {                // W8fT[e][u] = W8[u][e], e<200,u<100
        int o = gid - 30000; int e = o / 100; int u = o - 100 * e;
        W8fT[o] = W8[u * 200 + e];
    }
}

// ---------------- K0c: bl8f[l] = sum_u b8[u]*le[u][l] ----------------
__global__ __launch_bounds__(256) void k0c(const float* __restrict__ b8, const float* __restrict__ le,
                                           float* __restrict__ bl8f) {
    int l = blockIdx.x * 256 + threadIdx.x;
    if (l >= L_) return;
    float acc = 0.f;
    for (int u = 0; u < 100; u++) acc += b8[u] * le[u * 1000 + l];
    bl8f[l] = acc;
}

// ---------------- K0d: W7fT[p][k] = W7[k][p] * vvp[p] (transposed, vv folded) ----------------
__global__ __launch_bounds__(256) void k0d(const float* __restrict__ W7, const float* __restrict__ vvp,
                                           float* __restrict__ W7fT) {
    __shared__ float tile[100 * 65];
    __shared__ float vvs[64];
    int p0 = blockIdx.x * 64;
    int tid = threadIdx.x; int pl = tid & 63;
    int pcnt = min(64, NPAIR - p0);
    if (tid < 64) vvs[tid] = (p0 + tid < NPAIR) ? vvp[p0 + tid] : 0.f;
    __syncthreads();
    for (int kk = tid >> 6; kk < 100; kk += 4) {
        float w = (pl < pcnt) ? W7[kk * NPAIR + p0 + pl] : 0.f;
        tile[kk * 65 + pl] = w * vvs[pl];
    }
    __syncthreads();
    for (int o = tid; o < 6400; o += 256) {
        int pp = o / 100; int k = o - 100 * pp;
        if (pp < pcnt) W7fT[(size_t)(p0 + pp) * 100 + k] = tile[k * 65 + pp];
    }
}

// ---------------- K1: attention pools -> cat1[B][200] ----------------
__global__ __launch_bounds__(256) void k1(const float* __restrict__ x, const float* __restrict__ usf,
                                          const float* __restrict__ csf, float* __restrict__ cat1) {
    __shared__ float xs[N_ * 101];
    __shared__ float zs[2][64];
    __shared__ float wsm[2][64];
    __shared__ float uss[200];
    __shared__ float css[2];
    int b = blockIdx.x; int tid = threadIdx.x;
    const float* xr = x + (size_t)b * (N_ * E_);
    for (int li = tid; li < (N_ * E_) / 4; li += 256) {   // 1250 float4s
        float4 vv = ((const float4*)xr)[li];
        int flat = li * 4; int n = flat / 100; int e = flat - n * 100;
        float* d = xs + n * 101 + e;                       // e<=96, stays in row
        d[0] = vv.x; d[1] = vv.y; d[2] = vv.z; d[3] = vv.w;
    }
    if (tid < 200) uss[tid] = usf[tid];
    if (tid < 2) css[tid] = csf[tid];
    __syncthreads();
    if (tid < 100) {
        int h = (tid >= 50); int n = tid - 50 * h;
        float z = css[h];
        const float* u = uss + h * 100;
        for (int e = 0; e < 100; e++) z = fmaf(xs[n * 101 + e], u[e], z);
        zs[h][n] = expf(z);          // logits = exp(h @ W2^T)
    }
    __syncthreads();
    int wv = tid >> 6, ln = tid & 63;
    if (wv < 2) {
        float a = (ln < 50) ? zs[wv][ln] : -3.0e38f;
        float m = a;
        for (int s = 1; s < 64; s <<= 1) m = fmaxf(m, __shfl_xor(m, s, 64));
        float ex = (ln < 50) ? expf(a - m) : 0.f;
        float ss = ex;
        for (int s = 1; s < 64; s <<= 1) ss += __shfl_xor(ss, s, 64);
        if (ln < 50) wsm[wv][ln] = ex / ss;   // softmax over N
    }
    __syncthreads();
    if (tid < 200) {
        int h = (tid >= 100); int e = tid - 100 * h;
        float q = 0.f;
        for (int n = 0; n < 50; n++) q = fmaf(xs[n * 101 + e], wsm[h][n], q);
        cat1[(size_t)b * 200 + tid] = q;      // [q1 | q2]
    }
}

// ---------------- K2: h5, h6, cross-feature x W7 (pair-split x4, partial buffers) ----------
__global__ __launch_bounds__(256, 2) void k2(const float* __restrict__ cat1,
        const float* __restrict__ W5fT, const float* __restrict__ W6fT,
        const float* __restrict__ b5f, const float* __restrict__ b6f,
        const float* __restrict__ W7fT, const int* __restrict__ pairIJ,
        float* __restrict__ h6T, float* __restrict__ h7Tp) {
    __shared__ float bufA[8192];       // phase A: cat1 half-tile [64][101]; phase C: cf chunk [128][64]
    __shared__ float h5s[64 * 101];
    int g  = blockIdx.x >> 7;          // pair group 0..3
    int rb = blockIdx.x & 127;
    int r0 = rb * 64;
    int tid = threadIdx.x; int lane = tid & 63;
    int kbase = __builtin_amdgcn_readfirstlane((tid >> 6) * 25);  // wave-uniform k slice

    // ---- phase A: h5 = cat1 @ W5^T + b5, two 100-col half-tiles ----
    float acc2[25];
    #pragma unroll
    for (int m = 0; m < 25; m++) acc2[m] = b5f[kbase + m];
    for (int half = 0; half < 2; half++) {
        __syncthreads();
        for (int idx = tid; idx < 6400; idx += 256) {
            int r = idx / 100; int j = idx - r * 100;
            bufA[r * 101 + j] = cat1[(size_t)(r0 + r) * 200 + half * 100 + j];
        }
        __syncthreads();
        for (int j = 0; j < 100; j++) {
            float vv = bufA[lane * 101 + j];
            const float* wr = W5fT + (half * 100 + j) * 100 + kbase;   // uniform -> s_load
            #pragma unroll
            for (int m = 0; m < 25; m++) acc2[m] = fmaf(vv, wr[m], acc2[m]);
        }
    }
    #pragma unroll
    for (int m = 0; m < 25; m++) h5s[lane * 101 + kbase + m] = acc2[m];
    __syncthreads();

    // ---- phase B: h6 (group 0 only) ----
    if (g == 0) {
        #pragma unroll
        for (int m = 0; m < 25; m++) acc2[m] = b6f[kbase + m];
        for (int j = 0; j < 100; j++) {
            float vv = h5s[lane * 101 + j];
            const float* wr = W6fT + j * 100 + kbase;
            #pragma unroll
            for (int m = 0; m < 25; m++) acc2[m] = fmaf(vv, wr[m], acc2[m]);
        }
        #pragma unroll
        for (int m = 0; m < 25; m++) h6T[(size_t)(kbase + m) * B_ + r0 + lane] = acc2[m];
    }

    // ---- phase C: h7 partial over this group's pairs ----
    float acc[25];
    #pragma unroll
    for (int m = 0; m < 25; m++) acc[m] = 0.f;
    int pstart = g * 1238;
    int pend = min(NPAIR, pstart + 1238);
    for (int pc = pstart; pc < pend; pc += 128) {
        int PCc = min(128, pend - pc);
        __syncthreads();
        for (int idx = tid; idx < (PCc << 6); idx += 256) {
            int pl = idx >> 6; int rr = idx & 63;
            int ij = pairIJ[pc + pl];
            int i = ij >> 8, jj = ij & 255;
            bufA[(pl << 6) + rr] = h5s[rr * 101 + i] * h5s[rr * 101 + jj];
        }
        __syncthreads();
        for (int pl = 0; pl < PCc; pl++) {
            float vv = bufA[(pl << 6) + lane];
            const float* wr = W7fT + (size_t)(pc + pl) * 100 + kbase;  // uniform -> s_load
            #pragma unroll
            for (int m = 0; m < 25; m++) acc[m] = fmaf(vv, wr[m], acc[m]);
        }
    }
    float* h7p = h7Tp + (size_t)g * 100 * B_;
    #pragma unroll
    for (int m = 0; m < 25; m++)
        h7p[(size_t)(kbase + m) * B_ + r0 + lane] = acc[m];
}

// ---------------- K3a: h8T = W8 @ [h6; sum(h7 partials)+b7], one writer per element ----------
__global__ __launch_bounds__(256) void k3a(const float* __restrict__ h6T, const float* __restrict__ h7Tp,
        const float* __restrict__ b7f, const float* __restrict__ W8fT, float* __restrict__ h8T) {
    int tid = threadIdx.x; int lane = tid & 63;
    int ubase = __builtin_amdgcn_readfirstlane((tid >> 6) * 25);  // wave-uniform u slice
    int b = blockIdx.x * 64 + lane;
    float acc[25];
    #pragma unroll
    for (int m = 0; m < 25; m++) acc[m] = 0.f;
    for (int e = 0; e < 200; e++) {
        float vv;
        if (e < 100) {
            vv = h6T[(size_t)e * B_ + b];
        } else {
            int ee = e - 100;
            vv = h7Tp[(size_t)ee * B_ + b]
               + h7Tp[(size_t)(100 + ee) * B_ + b]
               + h7Tp[(size_t)(200 + ee) * B_ + b]
               + h7Tp[(size_t)(300 + ee) * B_ + b]
               + b7f[ee];
        }
        const float* wr = W8fT + e * 100 + ubase;   // uniform -> s_load
        #pragma unroll
        for (int m = 0; m < 25; m++) acc[m] = fmaf(vv, wr[m], acc[m]);
    }
    #pragma unroll
    for (int m = 0; m < 25; m++) h8T[(size_t)(ubase + m) * B_ + b] = acc[m];
}

// ---------------- K3b: out = h8 @ label_embedding (+ b8@le folded bias) ----------------
__global__ __launch_bounds__(256) void k3b(const float* __restrict__ h8T, const float* __restrict__ le,
        const float* __restrict__ bl8f, float* __restrict__ out) {
    int lq = blockIdx.x & 3; int bb = blockIdx.x >> 2;
    int b0 = bb * 32;
    int l = lq * 256 + threadIdx.x;
    bool valid = (l < L_);
    float acc[32];
    #pragma unroll
    for (int i = 0; i < 32; i++) acc[i] = 0.f;
    for (int u = 0; u < 100; u++) {
        float lev = valid ? le[u * 1000 + l] : 0.f;
        const float* hr = h8T + (size_t)u * B_ + b0;   // uniform -> s_load
        #pragma unroll
        for (int i = 0; i < 32; i++) acc[i] = fmaf(hr[i], lev, acc[i]);
    }
    if (valid) {
        float bias = bl8f[l];
        #pragma unroll
        for (int i = 0; i < 32; i++)
            out[(size_t)(b0 + i) * 1000 + l] = acc[i] + bias;
    }
}

extern "C" void kernel_launch(void* const* d_in, const int* in_sizes, int n_in,
                              void* d_out, int out_size, void* d_ws, size_t ws_size,
                              hipStream_t stream) {
    const float* x  = (const float*)d_in[0];
    const float* v  = (const float*)d_in[1];
    const float* W1 = (const float*)d_in[2];
    const float* b1 = (const float*)d_in[3];
    const float* W2 = (const float*)d_in[4];
    const float* W3 = (const float*)d_in[5];
    const float* b3 = (const float*)d_in[6];
    const float* W4 = (const float*)d_in[7];
    const float* W5 = (const float*)d_in[8];
    const float* b5 = (const float*)d_in[9];
    const float* W6 = (const float*)d_in[10];
    const float* b6 = (const float*)d_in[11];
    const float* W7 = (const float*)d_in[12];
    const float* b7 = (const float*)d_in[13];
    const float* W8 = (const float*)d_in[14];
    const float* b8 = (const float*)d_in[15];
    const float* le = (const float*)d_in[16];
    float* out = (float*)d_out;
    float* ws = (float*)d_ws;

    float* cat1   = ws;                 // 1,638,400
    float* h6T    = ws + 1638400;       //   819,200
    float* h7Tp   = ws + 2457600;       // 3,276,800 (4 partials x 100 x B)
    float* h8T    = ws + 5734400;       //   819,200
    float* W7fT   = ws + 6553600;       //   495,000
    float* W5fT   = ws + 7048600;       //    20,000
    float* W6fT   = ws + 7068600;       //    10,000
    float* W8fT   = ws + 7078600;       //    20,000
    float* usf    = ws + 7098600;       //       200
    float* csf    = ws + 7098800;       //       2 (+2 pad)
    float* b5f    = ws + 7098804;       //       100
    float* b6f    = ws + 7098904;       //       100
    float* b7f    = ws + 7099004;       //       100
    float* bl8f   = ws + 7099104;       //      1000
    float* vvp    = ws + 7100104;       //      4950
    int*   pairIJ = (int*)(ws + 7105054); //    4950

    k0a<<<1, 256, 0, stream>>>(v, W1, b1, W2, W3, b3, W4, b5, b6, b7,
                               usf, csf, b5f, b6f, b7f, vvp, pairIJ);
    k0b<<<196, 256, 0, stream>>>(W5, W6, W8, W5fT, W6fT, W8fT);
    k0c<<<4, 256, 0, stream>>>(b8, le, bl8f);
    k0d<<<78, 256, 0, stream>>>(W7, vvp, W7fT);
    k1<<<8192, 256, 0, stream>>>(x, usf, csf, cat1);
    k2<<<512, 256, 0, stream>>>(cat1, W5fT, W6fT, b5f, b6f, W7fT, pairIJ, h6T, h7Tp);
    k3a<<<128, 256, 0, stream>>>(h6T, h7Tp, b7f, W8fT, h8T);
    k3b<<<1024, 256, 0, stream>>>(h8T, le, bl8f, out);
}